// Round 8
// baseline (439.611 us; speedup 1.0000x reference)
//
#include <hip/hip_runtime.h>
#include <math.h>

#define BB 256
#define SSEQ 128
#define INPUT 256
#define PD 128
#define EE 64
#define RW 256
#define MM 512
#define WW 64
#define KD 384          // IN_DIM

typedef _Float16 half8 __attribute__((ext_vector_type(8)));
typedef __fp16 fp16x2 __attribute__((ext_vector_type(2)));
typedef float float4v __attribute__((ext_vector_type(4)));

#define LOG2E 1.44269504088896f
#define OUT1 8388608u

// LDS byte layout.
// Phase A (prologue): [0,128K) = Wq x-part f16 image, chunk c = (k>>3)*256 + n.
// Phase B (flash):    [0,64K)  = mem f16 rows (chunk m*8 + (c^(m&7))),
//                     [64K,128K) = memT f16 (chunk w*64 + (cm^(w&7))).
// [128K, 128K+6K) f32 scratch.
#define MEMT_OFF 65536
#define F32_OFF  131072
#define LDS_BYTES (131072 + 6144)
#define UE_O 0
#define PE_O 64
#define QPE_O 192
#define QP_O 448                  // qpart [1024]

union H8 { half8 h8; unsigned int u[4]; uint4 u4; };

__device__ __forceinline__ unsigned int pk2(float a, float b) {
    union { fp16x2 h; unsigned int u; } p;
    p.h = __builtin_amdgcn_cvt_pkrtz(a, b);
    return p.u;
}

// ---------- single fused kernel: 256 blocks x 1024 threads (16 waves) ----------
// launch_bounds (1024,4): 128-reg budget. (1024,8) forces 64 regs -> spills (R7: 2x slower).
__global__ void __launch_bounds__(1024, 4)
attn_kernel(const float* __restrict__ x, const int* __restrict__ user_id,
            const float* __restrict__ uet, const float* __restrict__ W_proc,
            const float* __restrict__ b_proc, const float* __restrict__ Wq,
            const float* __restrict__ memG, float* __restrict__ out)
{
    extern __shared__ char smraw[];
    unsigned short* smemu = (unsigned short*)smraw;
    unsigned int*   smw   = (unsigned int*)smraw;
    uint4*          sm128 = (uint4*)smraw;
    float*          smf   = (float*)(smraw + F32_OFF);

    const int t = threadIdx.x;
    const int b = blockIdx.x;
    const int lane = t & 63, wv = t >> 6;        // 16 waves
    const int n16 = lane & 15, quad = lane >> 4;
    const int r = wv & 3, sq = wv >> 2;          // sq 0..3
    const int s0 = sq * 32;
    const int swz = n16 & 7;
    const bool blast = (b == BB - 1);

    const int uid = user_id[b];
    const int sid = uid & 15;
    const float* memB = memG + (size_t)sid * (MM*WW);
    const float* wqX  = Wq + (size_t)sid * KD * RW;

    if (t < EE) smf[UE_O + t] = uet[(size_t)uid*EE + t];

    // ---- Prologue A: Wq x-part (k<256, n<256) -> LDS f16 image [k/8][n][k%8] ----
    for (int i = 0; i < 32; ++i) {
        int idx = i*1024 + t;                    // 0..32767
        int n = idx & 255, kp = idx >> 8;        // kp = k/2
        float w0 = wqX[(size_t)(2*kp)    *RW + n];
        float w1 = wqX[(size_t)(2*kp + 1)*RW + n];
        smw[((((kp>>2)*256 + n) << 2) | (kp & 3))] = pk2(w0, w1);
    }
    __syncthreads();

    // pe
    if (t < PD) {
        float a = b_proc[t];
        #pragma unroll
        for (int e = 0; e < EE; ++e) a = fmaf(smf[UE_O + e], W_proc[e*PD + t], a);
        smf[PE_O + t] = a;
    }
    __syncthreads();
    // qpe partials
    {
        int n = t & 255, h = t >> 8;
        float s = 0.f;
        const float* wr = wqX + (size_t)(256 + h*32)*RW + n;
        #pragma unroll 8
        for (int k = 0; k < 32; ++k) s = fmaf(smf[PE_O + h*32 + k], wr[(size_t)k*RW], s);
        smf[QP_O + h*256 + n] = s;
    }
    __syncthreads();
    if (t < 256) smf[QPE_O + t] = LOG2E * (smf[QP_O + t] + smf[QP_O + 256 + t]
                                         + smf[QP_O + 512 + t] + smf[QP_O + 768 + t]);
    __syncthreads();

    // ---- Phase Q (x-part k<256 only; pe via qpe bias; kc MUST stop at 8) ----
    float4v qacc[4][2];
    #pragma unroll
    for (int mt = 0; mt < 4; ++mt)
        #pragma unroll
        for (int nt = 0; nt < 2; ++nt) qacc[mt][nt] = (float4v)0.f;

    const float* xB = x + (size_t)(b*SSEQ + s0) * INPUT;
    for (int kc = 0; kc < 8; ++kc) {
        H8 afr[4];
        #pragma unroll
        for (int mt = 0; mt < 4; ++mt)
            afr[mt].u4 = sm128[(kc*4 + quad)*256 + r*64 + mt*16 + n16];
        H8 bfr[2];
        #pragma unroll
        for (int nt = 0; nt < 2; ++nt) {
            const float* xg = xB + (size_t)(nt*16 + n16)*INPUT + kc*32 + quad*8;
            float4 a0 = *(const float4*)xg;
            float4 a1 = *(const float4*)(xg + 4);
            bfr[nt].u[0] = pk2(a0.x*LOG2E, a0.y*LOG2E);
            bfr[nt].u[1] = pk2(a0.z*LOG2E, a0.w*LOG2E);
            bfr[nt].u[2] = pk2(a1.x*LOG2E, a1.y*LOG2E);
            bfr[nt].u[3] = pk2(a1.z*LOG2E, a1.w*LOG2E);
        }
        #pragma unroll
        for (int mt = 0; mt < 4; ++mt)
            #pragma unroll
            for (int nt = 0; nt < 2; ++nt)
                qacc[mt][nt] = __builtin_amdgcn_mfma_f32_16x16x32_f16(afr[mt].h8, bfr[nt].h8, qacc[mt][nt], 0, 0, 0);
    }
    #pragma unroll
    for (int mt = 0; mt < 4; ++mt)
        #pragma unroll
        for (int reg = 0; reg < 4; ++reg) {
            float qv = smf[QPE_O + r*64 + mt*16 + quad*4 + reg];
            #pragma unroll
            for (int nt = 0; nt < 2; ++nt) qacc[mt][nt][reg] += qv;
        }
    unsigned int pkq[4][2][2];
    #pragma unroll
    for (int mt = 0; mt < 4; ++mt)
        #pragma unroll
        for (int nt = 0; nt < 2; ++nt) {
            pkq[mt][nt][0] = pk2(qacc[mt][nt][0], qacc[mt][nt][1]);
            pkq[mt][nt][1] = pk2(qacc[mt][nt][2], qacc[mt][nt][3]);
        }
    unsigned int bq[2][2][4];
    #pragma unroll
    for (int kc2 = 0; kc2 < 2; ++kc2)
        #pragma unroll
        for (int nt = 0; nt < 2; ++nt)
            #pragma unroll
            for (int p = 0; p < 4; ++p) {
                int qp = ((quad & 1) << 1) | (p >> 1);
                int src = n16 + (qp << 4);
                int sr = p & 1;
                int lo  = __shfl((int)pkq[kc2*2    ][nt][sr], src, 64);
                int hiv = __shfl((int)pkq[kc2*2 + 1][nt][sr], src, 64);
                bq[kc2][nt][p] = (unsigned int)((quad < 2) ? lo : hiv);
            }
    __syncthreads();                             // all waves done reading Wq image

    // ---- Prologue B: overwrite LDS with mem f16 images (convert + transpose) ----
    for (int i = 0; i < 4; ++i) {
        int id = t + i*1024;
        int m = id >> 3, cw = id & 7;
        const float* g = memB + m*64 + cw*8;
        float4 a0 = *(const float4*)g;
        float4 a1 = *(const float4*)(g + 4);
        sm128[m*8 + (cw ^ (m & 7))] =
            make_uint4(pk2(a0.x,a0.y), pk2(a0.z,a0.w), pk2(a1.x,a1.y), pk2(a1.z,a1.w));
    }
    __syncthreads();
    for (int i = 0; i < 4; ++i) {
        int id = t + i*1024;
        int w = id & 63, cm = id >> 6;
        unsigned int uu[4];
        #pragma unroll
        for (int p = 0; p < 4; ++p) {
            int m0 = cm*8 + 2*p, m1 = m0 + 1;
            unsigned short lo = smemu[m0*64 + (((w>>3) ^ (m0&7))<<3) + (w&7)];
            unsigned short hi = smemu[m1*64 + (((w>>3) ^ (m1&7))<<3) + (w&7)];
            uu[p] = (unsigned int)lo | ((unsigned int)hi << 16);
        }
        sm128[(MEMT_OFF >> 4) + w*64 + (cm ^ (w & 7))] = make_uint4(uu[0],uu[1],uu[2],uu[3]);
    }
    __syncthreads();

    // ================= two-pass flash (no serial cross-lane chains) =================
    // Pass 1: per-lane max of scores only.
    float mxl[2] = {-1e30f, -1e30f};
    for (int mtile = 0; mtile < 16; ++mtile) {
        float4v Sa[2][2];
        #pragma unroll
        for (int msub = 0; msub < 2; ++msub)
            #pragma unroll
            for (int nt = 0; nt < 2; ++nt) Sa[msub][nt] = (float4v)0.f;
        #pragma unroll
        for (int msub = 0; msub < 2; ++msub) {
            int m = mtile*32 + msub*16 + n16;
            #pragma unroll
            for (int kc2 = 0; kc2 < 2; ++kc2) {
                H8 af; af.u4 = sm128[m*8 + ((kc2*4 + quad) ^ swz)];
                #pragma unroll
                for (int nt = 0; nt < 2; ++nt) {
                    H8 bf; bf.u[0]=bq[kc2][nt][0]; bf.u[1]=bq[kc2][nt][1];
                           bf.u[2]=bq[kc2][nt][2]; bf.u[3]=bq[kc2][nt][3];
                    Sa[msub][nt] = __builtin_amdgcn_mfma_f32_16x16x32_f16(af.h8, bf.h8, Sa[msub][nt], 0, 0, 0);
                }
            }
        }
        #pragma unroll
        for (int nt = 0; nt < 2; ++nt)
            #pragma unroll
            for (int msub = 0; msub < 2; ++msub)
                #pragma unroll
                for (int g = 0; g < 4; ++g) mxl[nt] = fmaxf(mxl[nt], Sa[msub][nt][g]);
    }
    float M[2];
    #pragma unroll
    for (int nt = 0; nt < 2; ++nt) {
        float m0 = fmaxf(mxl[nt], __shfl_xor(mxl[nt], 16, 64));
        M[nt] = fmaxf(m0, __shfl_xor(m0, 32, 64));
    }

    // Pass 2: recompute scores, exp2(S-M), deferred per-lane sum, PV accumulate.
    float4v Oa[4][2];
    #pragma unroll
    for (int wt = 0; wt < 4; ++wt)
        #pragma unroll
        for (int nt = 0; nt < 2; ++nt) Oa[wt][nt] = (float4v)0.f;
    float llp[2] = {0.f, 0.f};

    for (int mtile = 0; mtile < 16; ++mtile) {
        float4v Sa[2][2];
        #pragma unroll
        for (int msub = 0; msub < 2; ++msub)
            #pragma unroll
            for (int nt = 0; nt < 2; ++nt) Sa[msub][nt] = (float4v)0.f;
        #pragma unroll
        for (int msub = 0; msub < 2; ++msub) {
            int m = mtile*32 + msub*16 + n16;
            #pragma unroll
            for (int kc2 = 0; kc2 < 2; ++kc2) {
                H8 af; af.u4 = sm128[m*8 + ((kc2*4 + quad) ^ swz)];
                #pragma unroll
                for (int nt = 0; nt < 2; ++nt) {
                    H8 bf; bf.u[0]=bq[kc2][nt][0]; bf.u[1]=bq[kc2][nt][1];
                           bf.u[2]=bq[kc2][nt][2]; bf.u[3]=bq[kc2][nt][3];
                    Sa[msub][nt] = __builtin_amdgcn_mfma_f32_16x16x32_f16(af.h8, bf.h8, Sa[msub][nt], 0, 0, 0);
                }
            }
        }
        if (blast) {
            // store raw scores for the final_state epilogue (one block only)
            #pragma unroll
            for (int nt = 0; nt < 2; ++nt) {
                int s = s0 + nt*16 + n16;
                size_t base = (size_t)OUT1 + ((size_t)(s*4 + r) << 9) + mtile*32 + quad*4;
                #pragma unroll
                for (int msub = 0; msub < 2; ++msub)
                    *(float4*)&out[base + msub*16] =
                        make_float4(Sa[msub][nt][0], Sa[msub][nt][1], Sa[msub][nt][2], Sa[msub][nt][3]);
            }
        }
        unsigned int pkP[2][2][2];
        #pragma unroll
        for (int nt = 0; nt < 2; ++nt) {
            float pv[2][4];
            #pragma unroll
            for (int msub = 0; msub < 2; ++msub)
                #pragma unroll
                for (int g = 0; g < 4; ++g) {
                    pv[msub][g] = __builtin_amdgcn_exp2f(Sa[msub][nt][g] - M[nt]);
                    llp[nt] += pv[msub][g];
                }
            pkP[0][nt][0] = pk2(pv[0][0], pv[0][1]); pkP[0][nt][1] = pk2(pv[0][2], pv[0][3]);
            pkP[1][nt][0] = pk2(pv[1][0], pv[1][1]); pkP[1][nt][1] = pk2(pv[1][2], pv[1][3]);
        }
        unsigned int bp[2][4];
        #pragma unroll
        for (int nt = 0; nt < 2; ++nt)
            #pragma unroll
            for (int p = 0; p < 4; ++p) {
                int qp = ((quad & 1) << 1) | (p >> 1);
                int src = n16 + (qp << 4);
                int sr = p & 1;
                int lo  = __shfl((int)pkP[0][nt][sr], src, 64);
                int hiv = __shfl((int)pkP[1][nt][sr], src, 64);
                bp[nt][p] = (unsigned int)((quad < 2) ? lo : hiv);
            }
        #pragma unroll
        for (int wt = 0; wt < 4; ++wt) {
            H8 af; af.u4 = sm128[(MEMT_OFF >> 4) + (wt*16 + n16)*64 + ((mtile*4 + quad) ^ swz)];
            #pragma unroll
            for (int nt = 0; nt < 2; ++nt) {
                H8 bf; bf.u[0]=bp[nt][0]; bf.u[1]=bp[nt][1]; bf.u[2]=bp[nt][2]; bf.u[3]=bp[nt][3];
                Oa[wt][nt] = __builtin_amdgcn_mfma_f32_16x16x32_f16(af.h8, bf.h8, Oa[wt][nt], 0, 0, 0);
            }
        }
    }

    // ---- store read_words ----
    #pragma unroll
    for (int nt = 0; nt < 2; ++nt) {
        float ll = llp[nt];
        ll += __shfl_xor(ll, 16, 64);
        ll += __shfl_xor(ll, 32, 64);
        float inv = 1.0f / ll;
        int s = s0 + nt*16 + n16;
        #pragma unroll
        for (int wt = 0; wt < 4; ++wt) {
            float4 o = make_float4(Oa[wt][nt][0]*inv, Oa[wt][nt][1]*inv,
                                   Oa[wt][nt][2]*inv, Oa[wt][nt][3]*inv);
            *(float4*)&out[((size_t)(b*SSEQ + s)*4 + r)*WW + wt*16 + quad*4] = o;
        }
    }

    // ---- final_state epilogue (block 255 only): normalize stored raw scores ----
    if (blast) {
        __threadfence();
        __syncthreads();
        const int row = t >> 1, half = t & 1;     // 512 rows (s*4+r), 2 threads/row
        float* rp = out + OUT1 + ((size_t)row << 9) + (half << 8);
        float mx = -1e30f;
        for (int i = 0; i < 64; ++i) {
            float4 v = *(float4*)&rp[i*4];
            mx = fmaxf(mx, fmaxf(fmaxf(v.x, v.y), fmaxf(v.z, v.w)));
        }
        mx = fmaxf(mx, __shfl_xor(mx, 1, 64));
        float sum = 0.f;
        for (int i = 0; i < 64; ++i) {
            float4 v = *(float4*)&rp[i*4];
            v.x = __builtin_amdgcn_exp2f(v.x - mx);
            v.y = __builtin_amdgcn_exp2f(v.y - mx);
            v.z = __builtin_amdgcn_exp2f(v.z - mx);
            v.w = __builtin_amdgcn_exp2f(v.w - mx);
            sum += v.x + v.y + v.z + v.w;
            *(float4*)&rp[i*4] = v;
        }
        sum += __shfl_xor(sum, 1, 64);
        float inv2 = 1.0f / sum;
        for (int i = 0; i < 64; ++i) {
            float4 v = *(float4*)&rp[i*4];
            v.x *= inv2; v.y *= inv2; v.z *= inv2; v.w *= inv2;
            *(float4*)&rp[i*4] = v;
        }
    }
}

extern "C" void kernel_launch(void* const* d_in, const int* in_sizes, int n_in,
                              void* d_out, int out_size, void* d_ws, size_t ws_size,
                              hipStream_t stream) {
    const float* x    = (const float*)d_in[0];
    const int*   uid  = (const int*)  d_in[1];
    const float* uet  = (const float*)d_in[2];
    const float* Wp   = (const float*)d_in[3];
    const float* bp   = (const float*)d_in[4];
    const float* Wq   = (const float*)d_in[5];
    const float* mem  = (const float*)d_in[6];
    float* out = (float*)d_out;

    (void)hipFuncSetAttribute((const void*)attn_kernel,
                              hipFuncAttributeMaxDynamicSharedMemorySize, LDS_BYTES);
    attn_kernel<<<BB, 1024, LDS_BYTES, stream>>>(x, uid, uet, Wp, bp, Wq, mem, out);
}

// Round 9
// 434.350 us; speedup vs baseline: 1.0121x; 1.0121x over previous
//
#include <hip/hip_runtime.h>
#include <math.h>

#define BB 256
#define SSEQ 128
#define INPUT 256
#define PD 128
#define EE 64
#define RW 256
#define MM 512
#define WW 64
#define KD 384          // IN_DIM

typedef _Float16 half8 __attribute__((ext_vector_type(8)));
typedef __fp16 fp16x2 __attribute__((ext_vector_type(2)));
typedef float float4v __attribute__((ext_vector_type(4)));

#define LOG2E 1.44269504088896f
#define OUT1 8388608u

// LDS byte layout.
// Phase A (prologue): [0,128K) = Wq x-part f16 image, chunk c = (k>>3)*256 + n.
// Phase B (flash):    [0,64K)  = mem f16 rows (chunk m*8 + (c^(m&7))),
//                     [64K,128K) = memT f16 (chunk w*64 + (cm^(w&7))).
// [128K, 128K+6K) f32 scratch.
#define MEMT_OFF 65536
#define F32_OFF  131072
#define LDS_BYTES (131072 + 6144)
#define UE_O 0
#define PE_O 64
#define QPE_O 192
#define QP_O 448                  // qpart [1024]

union H8 { half8 h8; unsigned int u[4]; uint4 u4; };

__device__ __forceinline__ unsigned int pk2(float a, float b) {
    union { fp16x2 h; unsigned int u; } p;
    p.h = __builtin_amdgcn_cvt_pkrtz(a, b);
    return p.u;
}

// ---------- single fused kernel: 256 blocks x 1024 threads (16 waves) ----------
// launch_bounds (1024,4): 128-reg budget. (1024,8) forces 64 regs -> spills (R7, 2x slower).
// Do NOT restructure the flash loop into multiple passes: extended live ranges
// spill to scratch and collapse occupancy (R8, 4x slower).
__global__ void __launch_bounds__(1024, 4)
attn_kernel(const float* __restrict__ x, const int* __restrict__ user_id,
            const float* __restrict__ uet, const float* __restrict__ W_proc,
            const float* __restrict__ b_proc, const float* __restrict__ Wq,
            const float* __restrict__ memG, float* __restrict__ out)
{
    extern __shared__ char smraw[];
    unsigned short* smemu = (unsigned short*)smraw;
    unsigned int*   smw   = (unsigned int*)smraw;
    uint4*          sm128 = (uint4*)smraw;
    float*          smf   = (float*)(smraw + F32_OFF);

    const int t = threadIdx.x;
    const int b = blockIdx.x;
    const int lane = t & 63, wv = t >> 6;        // 16 waves
    const int n16 = lane & 15, quad = lane >> 4;
    const int r = wv & 3, sq = wv >> 2;          // sq 0..3
    const int s0 = sq * 32;
    const int swz = n16 & 7;
    const bool blast = (b == BB - 1);

    const int uid = user_id[b];
    const int sid = uid & 15;
    const float* memB = memG + (size_t)sid * (MM*WW);
    const float* wqX  = Wq + (size_t)sid * KD * RW;

    if (t < EE) smf[UE_O + t] = uet[(size_t)uid*EE + t];

    // ---- Prologue A: Wq x-part (k<256, n<256) -> LDS f16 image [k/8][n][k%8] ----
    for (int i = 0; i < 32; ++i) {
        int idx = i*1024 + t;                    // 0..32767
        int n = idx & 255, kp = idx >> 8;        // kp = k/2
        float w0 = wqX[(size_t)(2*kp)    *RW + n];
        float w1 = wqX[(size_t)(2*kp + 1)*RW + n];
        smw[((((kp>>2)*256 + n) << 2) | (kp & 3))] = pk2(w0, w1);
    }
    __syncthreads();

    // pe
    if (t < PD) {
        float a = b_proc[t];
        #pragma unroll
        for (int e = 0; e < EE; ++e) a = fmaf(smf[UE_O + e], W_proc[e*PD + t], a);
        smf[PE_O + t] = a;
    }
    __syncthreads();
    // qpe partials
    {
        int n = t & 255, h = t >> 8;
        float s = 0.f;
        const float* wr = wqX + (size_t)(256 + h*32)*RW + n;
        #pragma unroll 8
        for (int k = 0; k < 32; ++k) s = fmaf(smf[PE_O + h*32 + k], wr[(size_t)k*RW], s);
        smf[QP_O + h*256 + n] = s;
    }
    __syncthreads();
    if (t < 256) smf[QPE_O + t] = LOG2E * (smf[QP_O + t] + smf[QP_O + 256 + t]
                                         + smf[QP_O + 512 + t] + smf[QP_O + 768 + t]);
    __syncthreads();

    // ---- Phase Q (x-part k<256 only; pe via qpe bias; kc MUST stop at 8) ----
    float4v qacc[4][2];
    #pragma unroll
    for (int mt = 0; mt < 4; ++mt)
        #pragma unroll
        for (int nt = 0; nt < 2; ++nt) qacc[mt][nt] = (float4v)0.f;

    const float* xB = x + (size_t)(b*SSEQ + s0) * INPUT;
    for (int kc = 0; kc < 8; ++kc) {
        H8 afr[4];
        #pragma unroll
        for (int mt = 0; mt < 4; ++mt)
            afr[mt].u4 = sm128[(kc*4 + quad)*256 + r*64 + mt*16 + n16];
        H8 bfr[2];
        #pragma unroll
        for (int nt = 0; nt < 2; ++nt) {
            const float* xg = xB + (size_t)(nt*16 + n16)*INPUT + kc*32 + quad*8;
            float4 a0 = *(const float4*)xg;
            float4 a1 = *(const float4*)(xg + 4);
            bfr[nt].u[0] = pk2(a0.x*LOG2E, a0.y*LOG2E);
            bfr[nt].u[1] = pk2(a0.z*LOG2E, a0.w*LOG2E);
            bfr[nt].u[2] = pk2(a1.x*LOG2E, a1.y*LOG2E);
            bfr[nt].u[3] = pk2(a1.z*LOG2E, a1.w*LOG2E);
        }
        #pragma unroll
        for (int mt = 0; mt < 4; ++mt)
            #pragma unroll
            for (int nt = 0; nt < 2; ++nt)
                qacc[mt][nt] = __builtin_amdgcn_mfma_f32_16x16x32_f16(afr[mt].h8, bfr[nt].h8, qacc[mt][nt], 0, 0, 0);
    }
    #pragma unroll
    for (int mt = 0; mt < 4; ++mt)
        #pragma unroll
        for (int reg = 0; reg < 4; ++reg) {
            float qv = smf[QPE_O + r*64 + mt*16 + quad*4 + reg];
            #pragma unroll
            for (int nt = 0; nt < 2; ++nt) qacc[mt][nt][reg] += qv;
        }
    unsigned int pkq[4][2][2];
    #pragma unroll
    for (int mt = 0; mt < 4; ++mt)
        #pragma unroll
        for (int nt = 0; nt < 2; ++nt) {
            pkq[mt][nt][0] = pk2(qacc[mt][nt][0], qacc[mt][nt][1]);
            pkq[mt][nt][1] = pk2(qacc[mt][nt][2], qacc[mt][nt][3]);
        }
    unsigned int bq[2][2][4];
    #pragma unroll
    for (int kc2 = 0; kc2 < 2; ++kc2)
        #pragma unroll
        for (int nt = 0; nt < 2; ++nt)
            #pragma unroll
            for (int p = 0; p < 4; ++p) {
                int qp = ((quad & 1) << 1) | (p >> 1);
                int src = n16 + (qp << 4);
                int sr = p & 1;
                int lo  = __shfl((int)pkq[kc2*2    ][nt][sr], src, 64);
                int hiv = __shfl((int)pkq[kc2*2 + 1][nt][sr], src, 64);
                bq[kc2][nt][p] = (unsigned int)((quad < 2) ? lo : hiv);
            }
    __syncthreads();                             // all waves done reading Wq image

    // ---- Prologue B: overwrite LDS with mem f16 images (convert + transpose) ----
    for (int i = 0; i < 4; ++i) {
        int id = t + i*1024;
        int m = id >> 3, cw = id & 7;
        const float* g = memB + m*64 + cw*8;
        float4 a0 = *(const float4*)g;
        float4 a1 = *(const float4*)(g + 4);
        sm128[m*8 + (cw ^ (m & 7))] =
            make_uint4(pk2(a0.x,a0.y), pk2(a0.z,a0.w), pk2(a1.x,a1.y), pk2(a1.z,a1.w));
    }
    __syncthreads();
    for (int i = 0; i < 4; ++i) {
        int id = t + i*1024;
        int w = id & 63, cm = id >> 6;
        unsigned int uu[4];
        #pragma unroll
        for (int p = 0; p < 4; ++p) {
            int m0 = cm*8 + 2*p, m1 = m0 + 1;
            unsigned short lo = smemu[m0*64 + (((w>>3) ^ (m0&7))<<3) + (w&7)];
            unsigned short hi = smemu[m1*64 + (((w>>3) ^ (m1&7))<<3) + (w&7)];
            uu[p] = (unsigned int)lo | ((unsigned int)hi << 16);
        }
        sm128[(MEMT_OFF >> 4) + w*64 + (cm ^ (w & 7))] = make_uint4(uu[0],uu[1],uu[2],uu[3]);
    }
    __syncthreads();

    // ========== single-pass flash loop (R6 structure), deferred sum ==========
    float4v Oa[4][2];
    #pragma unroll
    for (int wt = 0; wt < 4; ++wt)
        #pragma unroll
        for (int nt = 0; nt < 2; ++nt) Oa[wt][nt] = (float4v)0.f;
    float Ml[2] = {-1e30f, -1e30f}, llp[2] = {0.f, 0.f};

    for (int mtile = 0; mtile < 16; ++mtile) {
        float4v Sa[2][2];
        #pragma unroll
        for (int msub = 0; msub < 2; ++msub)
            #pragma unroll
            for (int nt = 0; nt < 2; ++nt) Sa[msub][nt] = (float4v)0.f;
        #pragma unroll
        for (int msub = 0; msub < 2; ++msub) {
            int m = mtile*32 + msub*16 + n16;
            #pragma unroll
            for (int kc2 = 0; kc2 < 2; ++kc2) {
                H8 af; af.u4 = sm128[m*8 + ((kc2*4 + quad) ^ swz)];
                #pragma unroll
                for (int nt = 0; nt < 2; ++nt) {
                    H8 bf; bf.u[0]=bq[kc2][nt][0]; bf.u[1]=bq[kc2][nt][1];
                           bf.u[2]=bq[kc2][nt][2]; bf.u[3]=bq[kc2][nt][3];
                    Sa[msub][nt] = __builtin_amdgcn_mfma_f32_16x16x32_f16(af.h8, bf.h8, Sa[msub][nt], 0, 0, 0);
                }
            }
        }
        if (blast) {
            // raw scores for the final_state epilogue (one block only)
            #pragma unroll
            for (int nt = 0; nt < 2; ++nt) {
                int s = s0 + nt*16 + n16;
                size_t base = (size_t)OUT1 + ((size_t)(s*4 + r) << 9) + mtile*32 + quad*4;
                #pragma unroll
                for (int msub = 0; msub < 2; ++msub)
                    *(float4*)&out[base + msub*16] =
                        make_float4(Sa[msub][nt][0], Sa[msub][nt][1], Sa[msub][nt][2], Sa[msub][nt][3]);
            }
        }
        unsigned int pkP[2][2][2];
        #pragma unroll
        for (int nt = 0; nt < 2; ++nt) {
            float tm = Sa[0][nt][0];
            #pragma unroll
            for (int g = 1; g < 4; ++g) tm = fmaxf(tm, Sa[0][nt][g]);
            #pragma unroll
            for (int g = 0; g < 4; ++g) tm = fmaxf(tm, Sa[1][nt][g]);
            tm = fmaxf(tm, __shfl_xor(tm, 16, 64));
            tm = fmaxf(tm, __shfl_xor(tm, 32, 64));
            float Mn = fmaxf(Ml[nt], tm);
            float al = __builtin_amdgcn_exp2f(Ml[nt] - Mn);
            float pv[2][4]; float ts = 0.f;
            #pragma unroll
            for (int msub = 0; msub < 2; ++msub)
                #pragma unroll
                for (int g = 0; g < 4; ++g) {
                    pv[msub][g] = __builtin_amdgcn_exp2f(Sa[msub][nt][g] - Mn);
                    ts += pv[msub][g];
                }
            llp[nt] = al*llp[nt] + ts;           // per-lane partial; reduced once at the end
            Ml[nt] = Mn;
            pkP[0][nt][0] = pk2(pv[0][0], pv[0][1]); pkP[0][nt][1] = pk2(pv[0][2], pv[0][3]);
            pkP[1][nt][0] = pk2(pv[1][0], pv[1][1]); pkP[1][nt][1] = pk2(pv[1][2], pv[1][3]);
            #pragma unroll
            for (int wt = 0; wt < 4; ++wt)
                #pragma unroll
                for (int g = 0; g < 4; ++g) Oa[wt][nt][g] *= al;
        }
        unsigned int bp[2][4];
        #pragma unroll
        for (int nt = 0; nt < 2; ++nt)
            #pragma unroll
            for (int p = 0; p < 4; ++p) {
                int qp = ((quad & 1) << 1) | (p >> 1);
                int src = n16 + (qp << 4);
                int sr = p & 1;
                int lo  = __shfl((int)pkP[0][nt][sr], src, 64);
                int hiv = __shfl((int)pkP[1][nt][sr], src, 64);
                bp[nt][p] = (unsigned int)((quad < 2) ? lo : hiv);
            }
        #pragma unroll
        for (int wt = 0; wt < 4; ++wt) {
            H8 af; af.u4 = sm128[(MEMT_OFF >> 4) + (wt*16 + n16)*64 + ((mtile*4 + quad) ^ swz)];
            #pragma unroll
            for (int nt = 0; nt < 2; ++nt) {
                H8 bf; bf.u[0]=bp[nt][0]; bf.u[1]=bp[nt][1]; bf.u[2]=bp[nt][2]; bf.u[3]=bp[nt][3];
                Oa[wt][nt] = __builtin_amdgcn_mfma_f32_16x16x32_f16(af.h8, bf.h8, Oa[wt][nt], 0, 0, 0);
            }
        }
    }

    // ---- store read_words ----
    #pragma unroll
    for (int nt = 0; nt < 2; ++nt) {
        float ll = llp[nt];
        ll += __shfl_xor(ll, 16, 64);
        ll += __shfl_xor(ll, 32, 64);
        float inv = 1.0f / ll;
        int s = s0 + nt*16 + n16;
        #pragma unroll
        for (int wt = 0; wt < 4; ++wt) {
            float4 o = make_float4(Oa[wt][nt][0]*inv, Oa[wt][nt][1]*inv,
                                   Oa[wt][nt][2]*inv, Oa[wt][nt][3]*inv);
            *(float4*)&out[((size_t)(b*SSEQ + s)*4 + r)*WW + wt*16 + quad*4] = o;
        }
    }

    // ---- final_state epilogue (block 255 only): normalize stored raw scores ----
    if (blast) {
        __threadfence_block();
        __syncthreads();
        const int row = t >> 1, half = t & 1;     // 512 rows (s*4+r), 2 threads/row
        float* rp = out + OUT1 + ((size_t)row << 9) + (half << 8);
        float mx = -1e30f;
        for (int i = 0; i < 64; ++i) {
            float4 v = *(float4*)&rp[i*4];
            mx = fmaxf(mx, fmaxf(fmaxf(v.x, v.y), fmaxf(v.z, v.w)));
        }
        mx = fmaxf(mx, __shfl_xor(mx, 1, 64));
        float sum = 0.f;
        for (int i = 0; i < 64; ++i) {
            float4 v = *(float4*)&rp[i*4];
            v.x = __builtin_amdgcn_exp2f(v.x - mx);
            v.y = __builtin_amdgcn_exp2f(v.y - mx);
            v.z = __builtin_amdgcn_exp2f(v.z - mx);
            v.w = __builtin_amdgcn_exp2f(v.w - mx);
            sum += v.x + v.y + v.z + v.w;
            *(float4*)&rp[i*4] = v;
        }
        sum += __shfl_xor(sum, 1, 64);
        float inv2 = 1.0f / sum;
        for (int i = 0; i < 64; ++i) {
            float4 v = *(float4*)&rp[i*4];
            v.x *= inv2; v.y *= inv2; v.z *= inv2; v.w *= inv2;
            *(float4*)&rp[i*4] = v;
        }
    }
}

extern "C" void kernel_launch(void* const* d_in, const int* in_sizes, int n_in,
                              void* d_out, int out_size, void* d_ws, size_t ws_size,
                              hipStream_t stream) {
    const float* x    = (const float*)d_in[0];
    const int*   uid  = (const int*)  d_in[1];
    const float* uet  = (const float*)d_in[2];
    const float* Wp   = (const float*)d_in[3];
    const float* bp   = (const float*)d_in[4];
    const float* Wq   = (const float*)d_in[5];
    const float* mem  = (const float*)d_in[6];
    float* out = (float*)d_out;

    (void)hipFuncSetAttribute((const void*)attn_kernel,
                              hipFuncAttributeMaxDynamicSharedMemorySize, LDS_BYTES);
    attn_kernel<<<BB, 1024, LDS_BYTES, stream>>>(x, uid, uet, Wp, bp, Wq, mem, out);
}

// Round 10
// 167.961 us; speedup vs baseline: 2.6173x; 2.5860x over previous
//
#include <hip/hip_runtime.h>
#include <math.h>

#define BB 256
#define SSEQ 128
#define INPUT 256
#define PD 128
#define EE 64
#define RW 256
#define MM 512
#define WW 64
#define KD 384          // IN_DIM

typedef _Float16 half8 __attribute__((ext_vector_type(8)));
typedef __fp16 fp16x2 __attribute__((ext_vector_type(2)));
typedef float float4v __attribute__((ext_vector_type(4)));

#define LOG2E 1.44269504088896f
#define OUT1 8388608u

// LDS byte layout.
// Phase A (prologue): [0,128K) = Wq x-part f16 image, chunk c = (k>>3)*256 + n.
// Phase B (flash):    [0,64K)  = mem f16 rows (chunk m*8 + (c^(m&7))),
//                     [64K,128K) = memT f16 (chunk w*64 + (cm^(w&7))).
// [128K, 128K+6K) f32 scratch.
#define MEMT_OFF 65536
#define F32_OFF  131072
#define LDS_BYTES (131072 + 6144)
#define UE_O 0
#define PE_O 64
#define QPE_O 192
#define QP_O 448                  // qpart [1024]

union H8 { half8 h8; unsigned int u[4]; uint4 u4; };

__device__ __forceinline__ unsigned int pk2(float a, float b) {
    union { fp16x2 h; unsigned int u; } p;
    p.h = __builtin_amdgcn_cvt_pkrtz(a, b);
    return p.u;
}

// ---------- single fused kernel: 256 blocks x 1024 threads (16 waves) ----------
// HARD-WON CONSTRAINTS (do not violate):
//  * launch_bounds (1024,4): forcing (1024,8) = 64-reg cap -> spills (R7, 2x slower).
//  * No multi-pass restructure of the flash loop (R8: spills, 4x slower).
//  * NEVER store/read MFMA accumulators (Sa) inside the loop beyond the exp/pack
//    path (R8/R9: forces accs into VGPR quads -> spill -> occupancy 6%).
__global__ void __launch_bounds__(1024, 4)
attn_kernel(const float* __restrict__ x, const int* __restrict__ user_id,
            const float* __restrict__ uet, const float* __restrict__ W_proc,
            const float* __restrict__ b_proc, const float* __restrict__ Wq,
            const float* __restrict__ memG, float* __restrict__ out)
{
    extern __shared__ char smraw[];
    unsigned short* smemu = (unsigned short*)smraw;
    unsigned int*   smw   = (unsigned int*)smraw;
    uint4*          sm128 = (uint4*)smraw;
    float*          smf   = (float*)(smraw + F32_OFF);

    const int t = threadIdx.x;
    const int b = blockIdx.x;
    const int lane = t & 63, wv = t >> 6;        // 16 waves
    const int n16 = lane & 15, quad = lane >> 4;
    const int r = wv & 3, sq = wv >> 2;          // sq 0..3
    const int s0 = sq * 32;
    const int swz = n16 & 7;

    const int uid = user_id[b];
    const int sid = uid & 15;
    const float* memB = memG + (size_t)sid * (MM*WW);
    const float* wqX  = Wq + (size_t)sid * KD * RW;

    if (t < EE) smf[UE_O + t] = uet[(size_t)uid*EE + t];

    // ---- Prologue A: Wq x-part (k<256, n<256) -> LDS f16 image [k/8][n][k%8] ----
    for (int i = 0; i < 32; ++i) {
        int idx = i*1024 + t;                    // 0..32767
        int n = idx & 255, kp = idx >> 8;        // kp = k/2
        float w0 = wqX[(size_t)(2*kp)    *RW + n];
        float w1 = wqX[(size_t)(2*kp + 1)*RW + n];
        smw[((((kp>>2)*256 + n) << 2) | (kp & 3))] = pk2(w0, w1);
    }
    __syncthreads();

    // pe
    if (t < PD) {
        float a = b_proc[t];
        #pragma unroll
        for (int e = 0; e < EE; ++e) a = fmaf(smf[UE_O + e], W_proc[e*PD + t], a);
        smf[PE_O + t] = a;
    }
    __syncthreads();
    // qpe partials
    {
        int n = t & 255, h = t >> 8;
        float s = 0.f;
        const float* wr = wqX + (size_t)(256 + h*32)*RW + n;
        #pragma unroll 8
        for (int k = 0; k < 32; ++k) s = fmaf(smf[PE_O + h*32 + k], wr[(size_t)k*RW], s);
        smf[QP_O + h*256 + n] = s;
    }
    __syncthreads();
    if (t < 256) smf[QPE_O + t] = LOG2E * (smf[QP_O + t] + smf[QP_O + 256 + t]
                                         + smf[QP_O + 512 + t] + smf[QP_O + 768 + t]);
    __syncthreads();

    // ---- Phase Q (x-part k<256 only; pe via qpe bias; kc MUST stop at 8) ----
    float4v qacc[4][2];
    #pragma unroll
    for (int mt = 0; mt < 4; ++mt)
        #pragma unroll
        for (int nt = 0; nt < 2; ++nt) qacc[mt][nt] = (float4v)0.f;

    const float* xB = x + (size_t)(b*SSEQ + s0) * INPUT;
    for (int kc = 0; kc < 8; ++kc) {
        H8 afr[4];
        #pragma unroll
        for (int mt = 0; mt < 4; ++mt)
            afr[mt].u4 = sm128[(kc*4 + quad)*256 + r*64 + mt*16 + n16];
        H8 bfr[2];
        #pragma unroll
        for (int nt = 0; nt < 2; ++nt) {
            const float* xg = xB + (size_t)(nt*16 + n16)*INPUT + kc*32 + quad*8;
            float4 a0 = *(const float4*)xg;
            float4 a1 = *(const float4*)(xg + 4);
            bfr[nt].u[0] = pk2(a0.x*LOG2E, a0.y*LOG2E);
            bfr[nt].u[1] = pk2(a0.z*LOG2E, a0.w*LOG2E);
            bfr[nt].u[2] = pk2(a1.x*LOG2E, a1.y*LOG2E);
            bfr[nt].u[3] = pk2(a1.z*LOG2E, a1.w*LOG2E);
        }
        #pragma unroll
        for (int mt = 0; mt < 4; ++mt)
            #pragma unroll
            for (int nt = 0; nt < 2; ++nt)
                qacc[mt][nt] = __builtin_amdgcn_mfma_f32_16x16x32_f16(afr[mt].h8, bfr[nt].h8, qacc[mt][nt], 0, 0, 0);
    }
    #pragma unroll
    for (int mt = 0; mt < 4; ++mt)
        #pragma unroll
        for (int reg = 0; reg < 4; ++reg) {
            float qv = smf[QPE_O + r*64 + mt*16 + quad*4 + reg];
            #pragma unroll
            for (int nt = 0; nt < 2; ++nt) qacc[mt][nt][reg] += qv;
        }
    unsigned int pkq[4][2][2];
    #pragma unroll
    for (int mt = 0; mt < 4; ++mt)
        #pragma unroll
        for (int nt = 0; nt < 2; ++nt) {
            pkq[mt][nt][0] = pk2(qacc[mt][nt][0], qacc[mt][nt][1]);
            pkq[mt][nt][1] = pk2(qacc[mt][nt][2], qacc[mt][nt][3]);
        }
    unsigned int bq[2][2][4];
    #pragma unroll
    for (int kc2 = 0; kc2 < 2; ++kc2)
        #pragma unroll
        for (int nt = 0; nt < 2; ++nt)
            #pragma unroll
            for (int p = 0; p < 4; ++p) {
                int qp = ((quad & 1) << 1) | (p >> 1);
                int src = n16 + (qp << 4);
                int sr = p & 1;
                int lo  = __shfl((int)pkq[kc2*2    ][nt][sr], src, 64);
                int hiv = __shfl((int)pkq[kc2*2 + 1][nt][sr], src, 64);
                bq[kc2][nt][p] = (unsigned int)((quad < 2) ? lo : hiv);
            }
    __syncthreads();                             // all waves done reading Wq image

    // ---- Prologue B: overwrite LDS with mem f16 images (convert + transpose) ----
    for (int i = 0; i < 4; ++i) {
        int id = t + i*1024;
        int m = id >> 3, cw = id & 7;
        const float* g = memB + m*64 + cw*8;
        float4 a0 = *(const float4*)g;
        float4 a1 = *(const float4*)(g + 4);
        sm128[m*8 + (cw ^ (m & 7))] =
            make_uint4(pk2(a0.x,a0.y), pk2(a0.z,a0.w), pk2(a1.x,a1.y), pk2(a1.z,a1.w));
    }
    __syncthreads();
    for (int i = 0; i < 4; ++i) {
        int id = t + i*1024;
        int w = id & 63, cm = id >> 6;
        unsigned int uu[4];
        #pragma unroll
        for (int p = 0; p < 4; ++p) {
            int m0 = cm*8 + 2*p, m1 = m0 + 1;
            unsigned short lo = smemu[m0*64 + (((w>>3) ^ (m0&7))<<3) + (w&7)];
            unsigned short hi = smemu[m1*64 + (((w>>3) ^ (m1&7))<<3) + (w&7)];
            uu[p] = (unsigned int)lo | ((unsigned int)hi << 16);
        }
        sm128[(MEMT_OFF >> 4) + w*64 + (cm ^ (w & 7))] = make_uint4(uu[0],uu[1],uu[2],uu[3]);
    }
    __syncthreads();

    // ========== single-pass flash loop (R6 structure; deferred denominator) ==========
    float4v Oa[4][2];
    #pragma unroll
    for (int wt = 0; wt < 4; ++wt)
        #pragma unroll
        for (int nt = 0; nt < 2; ++nt) Oa[wt][nt] = (float4v)0.f;
    float Ml[2] = {-1e30f, -1e30f}, llp[2] = {0.f, 0.f};

    for (int mtile = 0; mtile < 16; ++mtile) {
        float4v Sa[2][2];
        #pragma unroll
        for (int msub = 0; msub < 2; ++msub)
            #pragma unroll
            for (int nt = 0; nt < 2; ++nt) Sa[msub][nt] = (float4v)0.f;
        #pragma unroll
        for (int msub = 0; msub < 2; ++msub) {
            int m = mtile*32 + msub*16 + n16;
            #pragma unroll
            for (int kc2 = 0; kc2 < 2; ++kc2) {
                H8 af; af.u4 = sm128[m*8 + ((kc2*4 + quad) ^ swz)];
                #pragma unroll
                for (int nt = 0; nt < 2; ++nt) {
                    H8 bf; bf.u[0]=bq[kc2][nt][0]; bf.u[1]=bq[kc2][nt][1];
                           bf.u[2]=bq[kc2][nt][2]; bf.u[3]=bq[kc2][nt][3];
                    Sa[msub][nt] = __builtin_amdgcn_mfma_f32_16x16x32_f16(af.h8, bf.h8, Sa[msub][nt], 0, 0, 0);
                }
            }
        }
        unsigned int pkP[2][2][2];
        #pragma unroll
        for (int nt = 0; nt < 2; ++nt) {
            float tm = Sa[0][nt][0];
            #pragma unroll
            for (int g = 1; g < 4; ++g) tm = fmaxf(tm, Sa[0][nt][g]);
            #pragma unroll
            for (int g = 0; g < 4; ++g) tm = fmaxf(tm, Sa[1][nt][g]);
            tm = fmaxf(tm, __shfl_xor(tm, 16, 64));
            tm = fmaxf(tm, __shfl_xor(tm, 32, 64));
            float Mn = fmaxf(Ml[nt], tm);
            float al = __builtin_amdgcn_exp2f(Ml[nt] - Mn);
            float pv[2][4]; float ts = 0.f;
            #pragma unroll
            for (int msub = 0; msub < 2; ++msub)
                #pragma unroll
                for (int g = 0; g < 4; ++g) {
                    pv[msub][g] = __builtin_amdgcn_exp2f(Sa[msub][nt][g] - Mn);
                    ts += pv[msub][g];
                }
            llp[nt] = al*llp[nt] + ts;           // per-lane partial (al uniform per row)
            Ml[nt] = Mn;
            pkP[0][nt][0] = pk2(pv[0][0], pv[0][1]); pkP[0][nt][1] = pk2(pv[0][2], pv[0][3]);
            pkP[1][nt][0] = pk2(pv[1][0], pv[1][1]); pkP[1][nt][1] = pk2(pv[1][2], pv[1][3]);
            #pragma unroll
            for (int wt = 0; wt < 4; ++wt)
                #pragma unroll
                for (int g = 0; g < 4; ++g) Oa[wt][nt][g] *= al;
        }
        unsigned int bp[2][4];
        #pragma unroll
        for (int nt = 0; nt < 2; ++nt)
            #pragma unroll
            for (int p = 0; p < 4; ++p) {
                int qp = ((quad & 1) << 1) | (p >> 1);
                int src = n16 + (qp << 4);
                int sr = p & 1;
                int lo  = __shfl((int)pkP[0][nt][sr], src, 64);
                int hiv = __shfl((int)pkP[1][nt][sr], src, 64);
                bp[nt][p] = (unsigned int)((quad < 2) ? lo : hiv);
            }
        #pragma unroll
        for (int wt = 0; wt < 4; ++wt) {
            H8 af; af.u4 = sm128[(MEMT_OFF >> 4) + (wt*16 + n16)*64 + ((mtile*4 + quad) ^ swz)];
            #pragma unroll
            for (int nt = 0; nt < 2; ++nt) {
                H8 bf; bf.u[0]=bp[nt][0]; bf.u[1]=bp[nt][1]; bf.u[2]=bp[nt][2]; bf.u[3]=bp[nt][3];
                Oa[wt][nt] = __builtin_amdgcn_mfma_f32_16x16x32_f16(af.h8, bf.h8, Oa[wt][nt], 0, 0, 0);
            }
        }
    }

    // reduce deferred denominators (uniform across quads after this)
    float inv[2];
    #pragma unroll
    for (int nt = 0; nt < 2; ++nt) {
        float ll = llp[nt];
        ll += __shfl_xor(ll, 16, 64);
        ll += __shfl_xor(ll, 32, 64);
        inv[nt] = 1.0f / ll;
    }

    // ---- store read_words ----
    #pragma unroll
    for (int nt = 0; nt < 2; ++nt) {
        int s = s0 + nt*16 + n16;
        #pragma unroll
        for (int wt = 0; wt < 4; ++wt) {
            float4 o = make_float4(Oa[wt][nt][0]*inv[nt], Oa[wt][nt][1]*inv[nt],
                                   Oa[wt][nt][2]*inv[nt], Oa[wt][nt][3]*inv[nt]);
            *(float4*)&out[((size_t)(b*SSEQ + s)*4 + r)*WW + wt*16 + quad*4] = o;
        }
    }

    // ---- final_state (b == 255): recompute scores, store normalized wts (R6 tail) ----
    if (b == BB - 1) {
        for (int mtile = 0; mtile < 16; ++mtile) {
            float4v Sa[2][2];
            #pragma unroll
            for (int msub = 0; msub < 2; ++msub)
                #pragma unroll
                for (int nt = 0; nt < 2; ++nt) Sa[msub][nt] = (float4v)0.f;
            #pragma unroll
            for (int msub = 0; msub < 2; ++msub) {
                int m = mtile*32 + msub*16 + n16;
                #pragma unroll
                for (int kc2 = 0; kc2 < 2; ++kc2) {
                    H8 af; af.u4 = sm128[m*8 + ((kc2*4 + quad) ^ swz)];
                    #pragma unroll
                    for (int nt = 0; nt < 2; ++nt) {
                        H8 bf; bf.u[0]=bq[kc2][nt][0]; bf.u[1]=bq[kc2][nt][1];
                               bf.u[2]=bq[kc2][nt][2]; bf.u[3]=bq[kc2][nt][3];
                        Sa[msub][nt] = __builtin_amdgcn_mfma_f32_16x16x32_f16(af.h8, bf.h8, Sa[msub][nt], 0, 0, 0);
                    }
                }
            }
            #pragma unroll
            for (int nt = 0; nt < 2; ++nt) {
                int s = s0 + nt*16 + n16;
                size_t base = (size_t)OUT1 + ((size_t)(s*4 + r) << 9);
                #pragma unroll
                for (int msub = 0; msub < 2; ++msub) {
                    float4 w4 = make_float4(
                        __builtin_amdgcn_exp2f(Sa[msub][nt][0] - Ml[nt]) * inv[nt],
                        __builtin_amdgcn_exp2f(Sa[msub][nt][1] - Ml[nt]) * inv[nt],
                        __builtin_amdgcn_exp2f(Sa[msub][nt][2] - Ml[nt]) * inv[nt],
                        __builtin_amdgcn_exp2f(Sa[msub][nt][3] - Ml[nt]) * inv[nt]);
                    *(float4*)&out[base + mtile*32 + msub*16 + quad*4] = w4;
                }
            }
        }
    }
}

extern "C" void kernel_launch(void* const* d_in, const int* in_sizes, int n_in,
                              void* d_out, int out_size, void* d_ws, size_t ws_size,
                              hipStream_t stream) {
    const float* x    = (const float*)d_in[0];
    const int*   uid  = (const int*)  d_in[1];
    const float* uet  = (const float*)d_in[2];
    const float* Wp   = (const float*)d_in[3];
    const float* bp   = (const float*)d_in[4];
    const float* Wq   = (const float*)d_in[5];
    const float* mem  = (const float*)d_in[6];
    float* out = (float*)d_out;

    (void)hipFuncSetAttribute((const void*)attn_kernel,
                              hipFuncAttributeMaxDynamicSharedMemorySize, LDS_BYTES);
    attn_kernel<<<BB, 1024, LDS_BYTES, stream>>>(x, uid, uet, Wp, bp, Wq, mem, out);
}